// Round 10
// baseline (197.310 us; speedup 1.0000x reference)
//
#include <hip/hip_runtime.h>
#include <math.h>

typedef __attribute__((ext_vector_type(4))) float f32x4;
typedef __attribute__((ext_vector_type(16))) float f32x16;
typedef __attribute__((ext_vector_type(8))) short bf16x8;
typedef __attribute__((ext_vector_type(4))) unsigned short us4;

#define T_SEQ 2048
#define NH 16
#define HD 64
#define CDIM 1024

__device__ __forceinline__ unsigned short f2bf(float f) {
  unsigned int u = __float_as_uint(f);
  u += 0x7fffu + ((u >> 16) & 1u);
  return (unsigned short)(u >> 16);
}

__device__ __forceinline__ f32x16 zero16() {
  f32x16 z;
#pragma unroll
  for (int i = 0; i < 16; ++i) z[i] = 0.0f;
  return z;
}

// global -> LDS direct (16B/lane, wave-uniform LDS base + lane*16)
#define GLOAD_LDS(g, l)                                                   \
  __builtin_amdgcn_global_load_lds(                                       \
      (const __attribute__((address_space(1))) unsigned int*)(g),         \
      (__attribute__((address_space(3))) unsigned int*)(l), 16, 0, 0)

// ---------------- cast x: fp32 -> bf16 ----------------
__global__ __launch_bounds__(256) void cast_x_kernel(const float* __restrict__ src,
                                                     unsigned short* __restrict__ dst,
                                                     int n4) {
  int i = blockIdx.x * 256 + threadIdx.x;
  if (i >= n4) return;
  f32x4 v = reinterpret_cast<const f32x4*>(src)[i];
  us4 o;
#pragma unroll
  for (int j = 0; j < 4; ++j) o[j] = f2bf(v[j]);
  reinterpret_cast<us4*>(dst)[i] = o;
}

// ------------- transpose + cast: W [K][N] fp32 -> W^T [N][K] bf16 -------------
__global__ __launch_bounds__(256) void transpose_cast_kernel(const float* __restrict__ src,
                                                             unsigned short* __restrict__ dst,
                                                             int ldsrc, int lddst) {
  __shared__ float tile[32][33];
  int n0 = blockIdx.x * 32, k0 = blockIdx.y * 32;
  int tx = threadIdx.x, ty = threadIdx.y;  // block (32,8)
#pragma unroll
  for (int r = 0; r < 4; ++r)
    tile[ty + r * 8][tx] = src[(size_t)(k0 + ty + r * 8) * ldsrc + n0 + tx];
  __syncthreads();
#pragma unroll
  for (int r = 0; r < 4; ++r)
    dst[(size_t)(n0 + ty + r * 8) * lddst + k0 + tx] = f2bf(tile[tx][ty + r * 8]);
}

// ---------------- RoPE table: cos/sin [T][32] fp32 ----------------
__global__ __launch_bounds__(256) void rope_table_kernel(float* __restrict__ cost,
                                                         float* __restrict__ sint) {
  int idx = blockIdx.x * 256 + threadIdx.x;  // 2048*32
  int t = idx >> 5, j = idx & 31;
  double invf = pow(10000.0, -(double)j / 32.0);
  double ang = (double)t * invf;
  cost[idx] = (float)cos(ang);
  sint[idx] = (float)sin(ang);
}

// ---------------- GEMM: C[M][N] = A[M][K] * B^T[N][K], bf16 in, fp32 acc ----
// Deep pipeline (T3+T4): BK=32, 4 LDS buffers (64KB), depth-3 prefetch.
// Tile loop top: asm vmcnt(8) + RAW s_barrier (never __syncthreads ->
// never vmcnt(0) in the loop). Proof: each wave issues 4 gloads/tile;
// allowing 8 outstanding (= tiles ti+1, ti+2) guarantees ti's loads landed
// per-wave; barrier makes it chip-wide and licenses overwriting
// buf[(ti+3)&3] (all waves finished reading it in iter ti-1 before their
// barrier). XOR swizzle cb^((row>>1)&3) both-sides -> 2-way residual (free).
// MODE 1: qkv epilogue with RoPE, fragment-major outputs
//   QF/KF[bh][blk32][ks][lane][8], VF[bh][t64][dgrp][ks][lane][8].
// MODE 0: plain fp32 store to out[M][N].
template <int MODE>
__global__ __launch_bounds__(256, 2) void gemm_kernel(
    const unsigned short* __restrict__ A, const unsigned short* __restrict__ Bt,
    int M, int N, int K,
    unsigned short* __restrict__ qo, unsigned short* __restrict__ ko,
    unsigned short* __restrict__ vTo, const float* __restrict__ cost,
    const float* __restrict__ sint, float* __restrict__ out) {
  __shared__ __align__(16) unsigned short As[4][128 * 32];  // 4 x 8KB
  __shared__ __align__(16) unsigned short Bs[4][128 * 32];  // 4 x 8KB
  const int tid = threadIdx.x;
  const int lane = tid & 63;
  const int wave = tid >> 6;
  const int wr = wave >> 1, wc = wave & 1;
  const int m0 = blockIdx.y * 128, n0 = blockIdx.x * 128;
  const int lrow = lane & 15, lhi = lane >> 4;
  // staging: chunk = 16 rows x 64B (one full BK row per 4 lanes); wave does
  // chunks wave*2..wave*2+1 per matrix (4 gloads/wave/tile).
  const int srow = lane >> 2;                           // row within chunk
  const int scol = ((lane & 3) ^ ((srow >> 1) & 3)) * 8;  // swizzled src col

  f32x4 zero4 = {0.f, 0.f, 0.f, 0.f};
  f32x4 acc[4][4];
#pragma unroll
  for (int mi = 0; mi < 4; ++mi)
#pragma unroll
    for (int ni = 0; ni < 4; ++ni) acc[mi][ni] = zero4;

  const int ntiles = K >> 5;  // BK=32
  auto stage = [&](int bf, int kt) {
#pragma unroll
    for (int c2 = 0; c2 < 2; ++c2) {
      const int c = wave * 2 + c2;  // chunk 0..7
      GLOAD_LDS(&A[(size_t)(m0 + c * 16 + srow) * K + kt + scol], &As[bf][c * 512]);
      GLOAD_LDS(&Bt[(size_t)(n0 + c * 16 + srow) * K + kt + scol], &Bs[bf][c * 512]);
    }
  };

  stage(0, 0);
  stage(1, 32);
  stage(2, 64);
  for (int ti = 0; ti < ntiles; ++ti) {
    // counted wait: my 4 loads for tile ti landed (<=8 newer stay in flight);
    // barrier -> ALL waves' ti loads landed AND buf[(ti+3)&3] free to overwrite
    asm volatile("s_waitcnt vmcnt(8)" ::: "memory");
    __builtin_amdgcn_s_barrier();
    __builtin_amdgcn_sched_barrier(0);
    if (ti + 3 < ntiles) stage((ti + 3) & 3, (ti + 3) * 32);
    const int cur = ti & 3;
    bf16x8 af[4], bfv[4];
#pragma unroll
    for (int i = 0; i < 4; ++i) {
      const int ra = wr * 64 + i * 16 + lrow;
      const int rb = wc * 64 + i * 16 + lrow;
      af[i] = *reinterpret_cast<const bf16x8*>(
          &As[cur][ra * 32 + (lhi ^ ((ra >> 1) & 3)) * 8]);
      bfv[i] = *reinterpret_cast<const bf16x8*>(
          &Bs[cur][rb * 32 + (lhi ^ ((rb >> 1) & 3)) * 8]);
    }
#pragma unroll
    for (int mi = 0; mi < 4; ++mi)
#pragma unroll
      for (int ni = 0; ni < 4; ++ni)
        acc[mi][ni] =
            __builtin_amdgcn_mfma_f32_16x16x32_bf16(af[mi], bfv[ni], acc[mi][ni], 0, 0, 0);
  }

  if (MODE == 0) {
#pragma unroll
    for (int mi = 0; mi < 4; ++mi)
#pragma unroll
      for (int ni = 0; ni < 4; ++ni) {
        int n = n0 + wc * 64 + ni * 16 + lrow;
#pragma unroll
        for (int r = 0; r < 4; ++r) {
          int m = m0 + wr * 64 + mi * 16 + lhi * 4 + r;
          out[(size_t)m * N + n] = acc[mi][ni][r];
        }
      }
  } else {
#pragma unroll
    for (int mi = 0; mi < 4; ++mi) {
      int mb = m0 + wr * 64 + mi * 16 + lhi * 4;  // 4 consecutive rows (t)
      int b = mb >> 11, tb = mb & (T_SEQ - 1);
#pragma unroll
      for (int ni = 0; ni < 4; ++ni) {
        int n = n0 + wc * 64 + ni * 16 + lrow;
        int sec = n >> 10;          // 0=q 1=k 2=v
        int h = (n >> 6) & 15;
        int d = n & 63;
        int bh_ = b * NH + h;
        if (sec == 2) {
          int t64 = tb >> 6, ks = (tb >> 4) & 3, hiv = (tb >> 3) & 1, e0 = tb & 7;
          int dgrp = d >> 5, lanev = hiv * 32 + (d & 31);
          us4 pk;
#pragma unroll
          for (int r = 0; r < 4; ++r) pk[r] = f2bf(acc[mi][ni][r]);
          size_t addr =
              ((((size_t)bh_ * 32 + t64) * 2 + dgrp) * 4 + ks) * 512 + lanev * 8 + e0;
          *reinterpret_cast<us4*>(&vTo[addr]) = pk;
        } else {
          int dm = d & 31;
          float sgn = (d < 32) ? -1.0f : 1.0f;
          unsigned short* dstp = (sec == 0) ? qo : ko;
          int ks = d >> 4, hiq = (d >> 3) & 1, e = d & 7;
#pragma unroll
          for (int r = 0; r < 4; ++r) {
            int t = tb + r;
            float c = cost[t * 32 + dm], s = sint[t * 32 + dm];
            float val = acc[mi][ni][r] * c + sgn * acc[mi][ni ^ 2][r] * s;
            if (sec == 0) val *= 0.125f;  // 1/sqrt(64) folded into q
            int blk = t >> 5, lane_ = hiq * 32 + (t & 31);
            dstp[(((size_t)bh_ * 64 + blk) * 4 + ks) * 512 + lane_ * 8 + e] = f2bf(val);
          }
        }
      }
    }
  }
}

// ---------------- flash attention, causal; 32x32 swapped-QK^T ----------------
// EXACT per-wave balance: wave owns q-blocks {p, 63-p}; myt(pos)=pos/2+1 so
// every wave processes exactly 33 kv-tiles -> no drain tail. 512 blocks
// (2/CU, 8 waves/CU). Register double-buffered K prefetch + early V issue.
// Fragment-major layouts (coalesced). In-register softmax; T13 defer-max;
// setprio around MFMA clusters.
__global__ __launch_bounds__(256, 2) void attn_kernel(const unsigned short* __restrict__ qg,
                                                      const unsigned short* __restrict__ kg,
                                                      const unsigned short* __restrict__ vtg,
                                                      unsigned short* __restrict__ att) {
  __shared__ __align__(16) unsigned short P[4][32][72];  // per-wave P buffer
  const int tid = threadIdx.x;
  const int lane = tid & 63;
  const int w = tid >> 6;
  const int l31 = lane & 31, hi = lane >> 5;
  const int bid = (int)blockIdx.x;
  const int xcd = bid & 7, j = bid >> 3;        // j 0..63
  const int bh = xcd * 8 + (j >> 3);            // 8 blocks per head
  const int p = (j & 7) * 4 + w;                // pair index 0..31
  const unsigned short* qfp = qg + (size_t)bh * 131072;
  const unsigned short* kfp = kg + (size_t)bh * 131072;
  const unsigned short* vfp = vtg + (size_t)bh * 131072;
  const int b = bh >> 4, h = bh & 15;

  auto run_pos = [&](int pos) {
    const int qrow = pos * 32 + l31;
    bf16x8 qf[4];
#pragma unroll
    for (int ks = 0; ks < 4; ++ks)
      qf[ks] =
          *reinterpret_cast<const bf16x8*>(&qfp[((size_t)pos * 4 + ks) * 512 + lane * 8]);
    f32x16 oA = zero16(), oB = zero16();
    float mrun = -3.0e38f, lrun = 0.0f;
    const int myt = (pos >> 1) + 1;

    bf16x8 kA0[4], kB0[4], kA1[4], kB1[4];
#pragma unroll
    for (int ks = 0; ks < 4; ++ks) {  // preload K tile 0
      kA0[ks] = *reinterpret_cast<const bf16x8*>(&kfp[(size_t)(0 + ks) * 512 + lane * 8]);
      kB0[ks] = *reinterpret_cast<const bf16x8*>(&kfp[(size_t)(4 + ks) * 512 + lane * 8]);
    }

    auto step = [&](int t, bf16x8 (&kcA)[4], bf16x8 (&kcB)[4], bf16x8 (&knA)[4],
                    bf16x8 (&knB)[4]) {
      // early V issue: consumed only after softmax -> latency hidden
      bf16x8 vA[4], vB[4];
#pragma unroll
      for (int ks = 0; ks < 4; ++ks) {
        vA[ks] = *reinterpret_cast<const bf16x8*>(
            &vfp[((size_t)(2 * t) * 4 + ks) * 512 + lane * 8]);
        vB[ks] = *reinterpret_cast<const bf16x8*>(
            &vfp[((size_t)(2 * t + 1) * 4 + ks) * 512 + lane * 8]);
      }
      // QK^T with current K (prefetched last iteration)
      f32x16 sA = zero16(), sB = zero16();
      __builtin_amdgcn_s_setprio(1);
#pragma unroll
      for (int ks = 0; ks < 4; ++ks) {
        sA = __builtin_amdgcn_mfma_f32_32x32x16_bf16(kcA[ks], qf[ks], sA, 0, 0, 0);
        sB = __builtin_amdgcn_mfma_f32_32x32x16_bf16(kcB[ks], qf[ks], sB, 0, 0, 0);
      }
      __builtin_amdgcn_s_setprio(0);
      // prefetch next K tile (used next iteration; hides under softmax+PV)
      if (t + 1 < myt) {
#pragma unroll
        for (int ks = 0; ks < 4; ++ks) {
          knA[ks] = *reinterpret_cast<const bf16x8*>(
              &kfp[((size_t)(2 * t + 2) * 4 + ks) * 512 + lane * 8]);
          knB[ks] = *reinterpret_cast<const bf16x8*>(
              &kfp[((size_t)(2 * t + 3) * 4 + ks) * 512 + lane * 8]);
        }
      }
      // causal mask (only final tile can contain future keys)
      if (t == myt - 1) {
        const int kvb = t * 64;
#pragma unroll
        for (int r = 0; r < 16; ++r) {
          int keyA = kvb + (r & 3) + 8 * (r >> 2) + 4 * hi;
          if (keyA > qrow) sA[r] = -1e30f;
          if (keyA + 32 > qrow) sB[r] = -1e30f;
        }
      }
      // in-register online softmax (per-lane scalars)
      float tr[16];
#pragma unroll
      for (int i = 0; i < 16; ++i) tr[i] = fmaxf(sA[i], sB[i]);
#pragma unroll
      for (int i = 0; i < 8; ++i) tr[i] = fmaxf(tr[i], tr[i + 8]);
#pragma unroll
      for (int i = 0; i < 4; ++i) tr[i] = fmaxf(tr[i], tr[i + 4]);
      float tm = fmaxf(fmaxf(tr[0], tr[1]), fmaxf(tr[2], tr[3]));
      tm = fmaxf(tm, __shfl_xor(tm, 32));  // merge lane halves (same query)
      // T13 defer-max: only rescale when max grew by > 8
      if (!__all(tm - mrun <= 8.0f)) {
        float mnew = fmaxf(mrun, tm);
        float alpha = __expf(mrun - mnew);
        lrun *= alpha;
#pragma unroll
        for (int i = 0; i < 16; ++i) {
          oA[i] *= alpha;
          oB[i] *= alpha;
        }
        mrun = mnew;
      }
#pragma unroll
      for (int i = 0; i < 16; ++i) {
        sA[i] = __expf(sA[i] - mrun);
        sB[i] = __expf(sB[i] - mrun);
      }
      float sr[16];
#pragma unroll
      for (int i = 0; i < 16; ++i) sr[i] = sA[i] + sB[i];
#pragma unroll
      for (int i = 0; i < 8; ++i) sr[i] += sr[i + 8];
#pragma unroll
      for (int i = 0; i < 4; ++i) sr[i] += sr[i + 4];
      float lsum = (sr[0] + sr[1]) + (sr[2] + sr[3]);
      lsum += __shfl_xor(lsum, 32);
      lrun += lsum;
      // P: S-layout -> [q][key] via per-wave LDS (no barrier needed)
#pragma unroll
      for (int g = 0; g < 4; ++g) {
        us4 pa, pb;
#pragma unroll
        for (int jj = 0; jj < 4; ++jj) {
          pa[jj] = f2bf(sA[4 * g + jj]);
          pb[jj] = f2bf(sB[4 * g + jj]);
        }
        *reinterpret_cast<us4*>(&P[w][l31][g * 8 + 4 * hi]) = pa;
        *reinterpret_cast<us4*>(&P[w][l31][32 + g * 8 + 4 * hi]) = pb;
      }
      // PV: O^T += mfma(V^T, P)
      __builtin_amdgcn_s_setprio(1);
#pragma unroll
      for (int ks = 0; ks < 4; ++ks) {
        bf16x8 pf = *reinterpret_cast<const bf16x8*>(&P[w][l31][ks * 16 + hi * 8]);
        oA = __builtin_amdgcn_mfma_f32_32x32x16_bf16(vA[ks], pf, oA, 0, 0, 0);
        oB = __builtin_amdgcn_mfma_f32_32x32x16_bf16(vB[ks], pf, oB, 0, 0, 0);
      }
      __builtin_amdgcn_s_setprio(0);
    };

    int t = 0;
    while (t < myt) {
      step(t, kA0, kB0, kA1, kB1);
      ++t;
      if (t >= myt) break;
      step(t, kA1, kB1, kA0, kB0);
      ++t;
    }

    const float inv = 1.0f / lrun;
    const size_t obase = ((size_t)b * T_SEQ + qrow) * CDIM + h * HD;
#pragma unroll
    for (int g = 0; g < 4; ++g) {
      us4 pa, pb;
#pragma unroll
      for (int jj = 0; jj < 4; ++jj) {
        pa[jj] = f2bf(oA[4 * g + jj] * inv);
        pb[jj] = f2bf(oB[4 * g + jj] * inv);
      }
      *reinterpret_cast<us4*>(&att[obase + g * 8 + 4 * hi]) = pa;
      *reinterpret_cast<us4*>(&att[obase + 32 + g * 8 + 4 * hi]) = pb;
    }
  };

  run_pos(63 - p);  // heavy half first (streams K/V, warms L2 for light half)
  run_pos(p);       // light half re-reads an L2-hot prefix
}

extern "C" void kernel_launch(void* const* d_in, const int* in_sizes, int n_in,
                              void* d_out, int out_size, void* d_ws, size_t ws_size,
                              hipStream_t stream) {
  const float* x = (const float*)d_in[0];
  const float* Wq = (const float*)d_in[1];
  const float* Wkv = (const float*)d_in[2];
  const float* Wc = (const float*)d_in[3];
  float* out = (float*)d_out;

  char* ws = (char*)d_ws;
  size_t off = 0;
  auto alloc = [&](size_t bytes) {
    void* p = ws + off;
    off += (bytes + 255) & ~(size_t)255;
    return p;
  };
  const size_t NTOK = 4ull * T_SEQ;            // 8192
  const size_t NELEM = NTOK * CDIM;            // 8388608
  unsigned short* xb = (unsigned short*)alloc(NELEM * 2);   // also reused for att
  unsigned short* WT = (unsigned short*)alloc(3072ull * 1024 * 2);
  unsigned short* WcT = (unsigned short*)alloc(1024ull * 1024 * 2);
  unsigned short* qb = (unsigned short*)alloc(NELEM * 2);
  unsigned short* kb = (unsigned short*)alloc(NELEM * 2);
  unsigned short* vT = (unsigned short*)alloc(NELEM * 2);
  float* cost = (float*)alloc(T_SEQ * 32 * 4);
  float* sint = (float*)alloc(T_SEQ * 32 * 4);
  unsigned short* att = xb;  // xb dead after gemm<1>; reuse for attention output

  cast_x_kernel<<<(int)(NELEM / 4 / 256), 256, 0, stream>>>(x, xb, (int)(NELEM / 4));
  transpose_cast_kernel<<<dim3(32, 32), dim3(32, 8), 0, stream>>>(Wq, WT, 1024, 1024);
  transpose_cast_kernel<<<dim3(64, 32), dim3(32, 8), 0, stream>>>(Wkv, WT + 1024 * 1024, 2048,
                                                                  1024);
  transpose_cast_kernel<<<dim3(32, 32), dim3(32, 8), 0, stream>>>(Wc, WcT, 1024, 1024);
  rope_table_kernel<<<T_SEQ * 32 / 256, 256, 0, stream>>>(cost, sint);

  gemm_kernel<1><<<dim3(3072 / 128, NTOK / 128), 256, 0, stream>>>(
      xb, WT, (int)NTOK, 3072, 1024, qb, kb, vT, cost, sint, nullptr);

  attn_kernel<<<dim3(512), 256, 0, stream>>>(qb, kb, vT, att);

  gemm_kernel<0><<<dim3(1024 / 128, NTOK / 128), 256, 0, stream>>>(
      att, WcT, (int)NTOK, 1024, 1024, nullptr, nullptr, nullptr, nullptr, nullptr, out);
}

// Round 11
// 177.281 us; speedup vs baseline: 1.1130x; 1.1130x over previous
//
#include <hip/hip_runtime.h>
#include <math.h>

typedef __attribute__((ext_vector_type(4))) float f32x4;
typedef __attribute__((ext_vector_type(16))) float f32x16;
typedef __attribute__((ext_vector_type(8))) short bf16x8;
typedef __attribute__((ext_vector_type(4))) unsigned short us4;

#define T_SEQ 2048
#define NH 16
#define HD 64
#define CDIM 1024

__device__ __forceinline__ unsigned short f2bf(float f) {
  unsigned int u = __float_as_uint(f);
  u += 0x7fffu + ((u >> 16) & 1u);
  return (unsigned short)(u >> 16);
}

__device__ __forceinline__ f32x16 zero16() {
  f32x16 z;
#pragma unroll
  for (int i = 0; i < 16; ++i) z[i] = 0.0f;
  return z;
}

// global -> LDS direct (16B/lane, wave-uniform LDS base + lane*16)
#define GLOAD_LDS(g, l)                                                   \
  __builtin_amdgcn_global_load_lds(                                       \
      (const __attribute__((address_space(1))) unsigned int*)(g),         \
      (__attribute__((address_space(3))) unsigned int*)(l), 16, 0, 0)

// ---------------- cast x: fp32 -> bf16 ----------------
__global__ __launch_bounds__(256) void cast_x_kernel(const float* __restrict__ src,
                                                     unsigned short* __restrict__ dst,
                                                     int n4) {
  int i = blockIdx.x * 256 + threadIdx.x;
  if (i >= n4) return;
  f32x4 v = reinterpret_cast<const f32x4*>(src)[i];
  us4 o;
#pragma unroll
  for (int j = 0; j < 4; ++j) o[j] = f2bf(v[j]);
  reinterpret_cast<us4*>(dst)[i] = o;
}

// ------------- transpose + cast: W [K][N] fp32 -> W^T [N][K] bf16 -------------
__global__ __launch_bounds__(256) void transpose_cast_kernel(const float* __restrict__ src,
                                                             unsigned short* __restrict__ dst,
                                                             int ldsrc, int lddst) {
  __shared__ float tile[32][33];
  int n0 = blockIdx.x * 32, k0 = blockIdx.y * 32;
  int tx = threadIdx.x, ty = threadIdx.y;  // block (32,8)
#pragma unroll
  for (int r = 0; r < 4; ++r)
    tile[ty + r * 8][tx] = src[(size_t)(k0 + ty + r * 8) * ldsrc + n0 + tx];
  __syncthreads();
#pragma unroll
  for (int r = 0; r < 4; ++r)
    dst[(size_t)(n0 + ty + r * 8) * lddst + k0 + tx] = f2bf(tile[tx][ty + r * 8]);
}

// ---------------- RoPE table: cos/sin [T][32] fp32 ----------------
__global__ __launch_bounds__(256) void rope_table_kernel(float* __restrict__ cost,
                                                         float* __restrict__ sint) {
  int idx = blockIdx.x * 256 + threadIdx.x;  // 2048*32
  int t = idx >> 5, j = idx & 31;
  double invf = pow(10000.0, -(double)j / 32.0);
  double ang = (double)t * invf;
  cost[idx] = (float)cos(ang);
  sint[idx] = (float)sin(ang);
}

// ---------------- GEMM: C[M][N] = A[M][K] * B^T[N][K], bf16 in, fp32 acc ----
// 2-phase double-buffered pipeline (R9, attested 682 TF): STAGE next K-tile
// via global_load_lds BEFORE computing current tile; ONE __syncthreads per
// tile. BK=64, 2x32KB LDS. XOR col-block swizzle both-sides (rule 21) ->
// 0 bank conflicts (verified R8). T4 counted-vmcnt graft REGRESSED (R10,
// -28%): do not re-add without the full 8-phase interleave.
// MODE 1: qkv epilogue with RoPE, fragment-major outputs
//   QF/KF[bh][blk32][ks][lane][8], VF[bh][t64][dgrp][ks][lane][8].
// MODE 0: plain fp32 store to out[M][N].
template <int MODE>
__global__ __launch_bounds__(256) void gemm_kernel(
    const unsigned short* __restrict__ A, const unsigned short* __restrict__ Bt,
    int M, int N, int K,
    unsigned short* __restrict__ qo, unsigned short* __restrict__ ko,
    unsigned short* __restrict__ vTo, const float* __restrict__ cost,
    const float* __restrict__ sint, float* __restrict__ out) {
  __shared__ __align__(16) unsigned short As[2][128 * 64];  // 2 x 16KB
  __shared__ __align__(16) unsigned short Bs[2][128 * 64];  // 2 x 16KB
  const int tid = threadIdx.x;
  const int lane = tid & 63;
  const int wave = tid >> 6;
  const int wr = wave >> 1, wc = wave & 1;
  const int m0 = blockIdx.y * 128, n0 = blockIdx.x * 128;
  const int lrow = lane & 15, lhi = lane >> 4;
  const int srow = lane >> 3;                  // row within 8-row chunk
  const int scol = (((lane & 7) ^ srow) * 8);  // swizzled source col (elems)

  f32x4 zero4 = {0.f, 0.f, 0.f, 0.f};
  f32x4 acc[4][4];
#pragma unroll
  for (int mi = 0; mi < 4; ++mi)
#pragma unroll
    for (int ni = 0; ni < 4; ++ni) acc[mi][ni] = zero4;

  const int ntiles = K >> 6;  // BK=64
  auto stage = [&](int bf, int kt) {
#pragma unroll
    for (int c2 = 0; c2 < 4; ++c2) {
      const int c = wave * 4 + c2;  // chunk 0..15 (8 rows x 128B each)
      GLOAD_LDS(&A[(size_t)(m0 + c * 8 + srow) * K + kt + scol], &As[bf][c * 512]);
      GLOAD_LDS(&Bt[(size_t)(n0 + c * 8 + srow) * K + kt + scol], &Bs[bf][c * 512]);
    }
  };

  stage(0, 0);
  __syncthreads();  // buf0 ready
  int cur = 0;
  for (int ti = 0; ti < ntiles; ++ti) {
    if (ti + 1 < ntiles) stage(cur ^ 1, (ti + 1) * 64);  // in flight under compute
#pragma unroll
    for (int kk = 0; kk < 2; ++kk) {
      bf16x8 af[4], bfv[4];
#pragma unroll
      for (int i = 0; i < 4; ++i) {
        const int ra = wr * 64 + i * 16 + lrow;
        const int rb = wc * 64 + i * 16 + lrow;
        const int cba = (kk * 4 + lhi) ^ (ra & 7);  // un-swizzle on read
        const int cbb = (kk * 4 + lhi) ^ (rb & 7);
        af[i] = *reinterpret_cast<const bf16x8*>(&As[cur][ra * 64 + cba * 8]);
        bfv[i] = *reinterpret_cast<const bf16x8*>(&Bs[cur][rb * 64 + cbb * 8]);
      }
#pragma unroll
      for (int mi = 0; mi < 4; ++mi)
#pragma unroll
        for (int ni = 0; ni < 4; ++ni)
          acc[mi][ni] =
              __builtin_amdgcn_mfma_f32_16x16x32_bf16(af[mi], bfv[ni], acc[mi][ni], 0, 0, 0);
    }
    __syncthreads();  // drains my gloads (flew under MFMA) + reads; swap safe
    cur ^= 1;
  }

  if (MODE == 0) {
#pragma unroll
    for (int mi = 0; mi < 4; ++mi)
#pragma unroll
      for (int ni = 0; ni < 4; ++ni) {
        int n = n0 + wc * 64 + ni * 16 + lrow;
#pragma unroll
        for (int r = 0; r < 4; ++r) {
          int m = m0 + wr * 64 + mi * 16 + lhi * 4 + r;
          out[(size_t)m * N + n] = acc[mi][ni][r];
        }
      }
  } else {
#pragma unroll
    for (int mi = 0; mi < 4; ++mi) {
      int mb = m0 + wr * 64 + mi * 16 + lhi * 4;  // 4 consecutive rows (t)
      int b = mb >> 11, tb = mb & (T_SEQ - 1);
#pragma unroll
      for (int ni = 0; ni < 4; ++ni) {
        int n = n0 + wc * 64 + ni * 16 + lrow;
        int sec = n >> 10;          // 0=q 1=k 2=v
        int h = (n >> 6) & 15;
        int d = n & 63;
        int bh_ = b * NH + h;
        if (sec == 2) {
          int t64 = tb >> 6, ks = (tb >> 4) & 3, hiv = (tb >> 3) & 1, e0 = tb & 7;
          int dgrp = d >> 5, lanev = hiv * 32 + (d & 31);
          us4 pk;
#pragma unroll
          for (int r = 0; r < 4; ++r) pk[r] = f2bf(acc[mi][ni][r]);
          size_t addr =
              ((((size_t)bh_ * 32 + t64) * 2 + dgrp) * 4 + ks) * 512 + lanev * 8 + e0;
          *reinterpret_cast<us4*>(&vTo[addr]) = pk;
        } else {
          int dm = d & 31;
          float sgn = (d < 32) ? -1.0f : 1.0f;
          unsigned short* dstp = (sec == 0) ? qo : ko;
          int ks = d >> 4, hiq = (d >> 3) & 1, e = d & 7;
#pragma unroll
          for (int r = 0; r < 4; ++r) {
            int t = tb + r;
            float c = cost[t * 32 + dm], s = sint[t * 32 + dm];
            float val = acc[mi][ni][r] * c + sgn * acc[mi][ni ^ 2][r] * s;
            if (sec == 0) val *= 0.125f;  // 1/sqrt(64) folded into q
            int blk = t >> 5, lane_ = hiq * 32 + (t & 31);
            dstp[(((size_t)bh_ * 64 + blk) * 4 + ks) * 512 + lane_ * 8 + e] = f2bf(val);
          }
        }
      }
    }
  }
}

// ---------------- flash attention, causal; 32x32 swapped-QK^T ----------------
// EXACT per-wave balance: wave owns q-blocks {p, 63-p} (33 kv-tiles each).
// 512 blocks (2/CU, 8 waves/CU). Register double-buffered K prefetch AND
// (new this round) V prefetch: V(t+1) issued right after QK(t) -> a full
// step (~800cy) of flight before PV consumes it, instead of only the
// QK+softmax window. Fragment-major layouts (coalesced). In-register
// softmax; T13 defer-max; setprio around MFMA clusters.
__global__ __launch_bounds__(256, 2) void attn_kernel(const unsigned short* __restrict__ qg,
                                                      const unsigned short* __restrict__ kg,
                                                      const unsigned short* __restrict__ vtg,
                                                      unsigned short* __restrict__ att) {
  __shared__ __align__(16) unsigned short P[4][32][72];  // per-wave P buffer
  const int tid = threadIdx.x;
  const int lane = tid & 63;
  const int w = tid >> 6;
  const int l31 = lane & 31, hi = lane >> 5;
  const int bid = (int)blockIdx.x;
  const int xcd = bid & 7, j = bid >> 3;        // j 0..63
  const int bh = xcd * 8 + (j >> 3);            // 8 blocks per head
  const int p = (j & 7) * 4 + w;                // pair index 0..31
  const unsigned short* qfp = qg + (size_t)bh * 131072;
  const unsigned short* kfp = kg + (size_t)bh * 131072;
  const unsigned short* vfp = vtg + (size_t)bh * 131072;
  const int b = bh >> 4, h = bh & 15;

  auto run_pos = [&](int pos) {
    const int qrow = pos * 32 + l31;
    bf16x8 qf[4];
#pragma unroll
    for (int ks = 0; ks < 4; ++ks)
      qf[ks] =
          *reinterpret_cast<const bf16x8*>(&qfp[((size_t)pos * 4 + ks) * 512 + lane * 8]);
    f32x16 oA = zero16(), oB = zero16();
    float mrun = -3.0e38f, lrun = 0.0f;
    const int myt = (pos >> 1) + 1;

    bf16x8 kA0[4], kB0[4], kA1[4], kB1[4];
    bf16x8 vA0[4], vB0[4], vA1[4], vB1[4];
#pragma unroll
    for (int ks = 0; ks < 4; ++ks) {  // preload K+V tile 0
      kA0[ks] = *reinterpret_cast<const bf16x8*>(&kfp[(size_t)(0 + ks) * 512 + lane * 8]);
      kB0[ks] = *reinterpret_cast<const bf16x8*>(&kfp[(size_t)(4 + ks) * 512 + lane * 8]);
      vA0[ks] = *reinterpret_cast<const bf16x8*>(&vfp[(size_t)(0 + ks) * 512 + lane * 8]);
      vB0[ks] = *reinterpret_cast<const bf16x8*>(&vfp[(size_t)(4 + ks) * 512 + lane * 8]);
    }

    auto step = [&](int t, bf16x8 (&kcA)[4], bf16x8 (&kcB)[4], bf16x8 (&knA)[4],
                    bf16x8 (&knB)[4], bf16x8 (&vcA)[4], bf16x8 (&vcB)[4],
                    bf16x8 (&vnA)[4], bf16x8 (&vnB)[4]) {
      // QK^T with current K (prefetched last iteration)
      f32x16 sA = zero16(), sB = zero16();
      __builtin_amdgcn_s_setprio(1);
#pragma unroll
      for (int ks = 0; ks < 4; ++ks) {
        sA = __builtin_amdgcn_mfma_f32_32x32x16_bf16(kcA[ks], qf[ks], sA, 0, 0, 0);
        sB = __builtin_amdgcn_mfma_f32_32x32x16_bf16(kcB[ks], qf[ks], sB, 0, 0, 0);
      }
      __builtin_amdgcn_s_setprio(0);
      // prefetch next K AND V tiles (consumed next iteration -> full-step flight)
      if (t + 1 < myt) {
#pragma unroll
        for (int ks = 0; ks < 4; ++ks) {
          knA[ks] = *reinterpret_cast<const bf16x8*>(
              &kfp[((size_t)(2 * t + 2) * 4 + ks) * 512 + lane * 8]);
          knB[ks] = *reinterpret_cast<const bf16x8*>(
              &kfp[((size_t)(2 * t + 3) * 4 + ks) * 512 + lane * 8]);
          vnA[ks] = *reinterpret_cast<const bf16x8*>(
              &vfp[((size_t)(2 * t + 2) * 4 + ks) * 512 + lane * 8]);
          vnB[ks] = *reinterpret_cast<const bf16x8*>(
              &vfp[((size_t)(2 * t + 3) * 4 + ks) * 512 + lane * 8]);
        }
      }
      // causal mask (only final tile can contain future keys)
      if (t == myt - 1) {
        const int kvb = t * 64;
#pragma unroll
        for (int r = 0; r < 16; ++r) {
          int keyA = kvb + (r & 3) + 8 * (r >> 2) + 4 * hi;
          if (keyA > qrow) sA[r] = -1e30f;
          if (keyA + 32 > qrow) sB[r] = -1e30f;
        }
      }
      // in-register online softmax (per-lane scalars)
      float tr[16];
#pragma unroll
      for (int i = 0; i < 16; ++i) tr[i] = fmaxf(sA[i], sB[i]);
#pragma unroll
      for (int i = 0; i < 8; ++i) tr[i] = fmaxf(tr[i], tr[i + 8]);
#pragma unroll
      for (int i = 0; i < 4; ++i) tr[i] = fmaxf(tr[i], tr[i + 4]);
      float tm = fmaxf(fmaxf(tr[0], tr[1]), fmaxf(tr[2], tr[3]));
      tm = fmaxf(tm, __shfl_xor(tm, 32));  // merge lane halves (same query)
      // T13 defer-max: only rescale when max grew by > 8
      if (!__all(tm - mrun <= 8.0f)) {
        float mnew = fmaxf(mrun, tm);
        float alpha = __expf(mrun - mnew);
        lrun *= alpha;
#pragma unroll
        for (int i = 0; i < 16; ++i) {
          oA[i] *= alpha;
          oB[i] *= alpha;
        }
        mrun = mnew;
      }
#pragma unroll
      for (int i = 0; i < 16; ++i) {
        sA[i] = __expf(sA[i] - mrun);
        sB[i] = __expf(sB[i] - mrun);
      }
      float sr[16];
#pragma unroll
      for (int i = 0; i < 16; ++i) sr[i] = sA[i] + sB[i];
#pragma unroll
      for (int i = 0; i < 8; ++i) sr[i] += sr[i + 8];
#pragma unroll
      for (int i = 0; i < 4; ++i) sr[i] += sr[i + 4];
      float lsum = (sr[0] + sr[1]) + (sr[2] + sr[3]);
      lsum += __shfl_xor(lsum, 32);
      lrun += lsum;
      // P: S-layout -> [q][key] via per-wave LDS (no barrier needed)
#pragma unroll
      for (int g = 0; g < 4; ++g) {
        us4 pa, pb;
#pragma unroll
        for (int jj = 0; jj < 4; ++jj) {
          pa[jj] = f2bf(sA[4 * g + jj]);
          pb[jj] = f2bf(sB[4 * g + jj]);
        }
        *reinterpret_cast<us4*>(&P[w][l31][g * 8 + 4 * hi]) = pa;
        *reinterpret_cast<us4*>(&P[w][l31][32 + g * 8 + 4 * hi]) = pb;
      }
      // PV: O^T += mfma(V^T, P); V was prefetched a full step ago
      __builtin_amdgcn_s_setprio(1);
#pragma unroll
      for (int ks = 0; ks < 4; ++ks) {
        bf16x8 pf = *reinterpret_cast<const bf16x8*>(&P[w][l31][ks * 16 + hi * 8]);
        oA = __builtin_amdgcn_mfma_f32_32x32x16_bf16(vcA[ks], pf, oA, 0, 0, 0);
        oB = __builtin_amdgcn_mfma_f32_32x32x16_bf16(vcB[ks], pf, oB, 0, 0, 0);
      }
      __builtin_amdgcn_s_setprio(0);
    };

    int t = 0;
    while (t < myt) {
      step(t, kA0, kB0, kA1, kB1, vA0, vB0, vA1, vB1);
      ++t;
      if (t >= myt) break;
      step(t, kA1, kB1, kA0, kB0, vA1, vB1, vA0, vB0);
      ++t;
    }

    const float inv = 1.0f / lrun;
    const size_t obase = ((size_t)b * T_SEQ + qrow) * CDIM + h * HD;
#pragma unroll
    for (int g = 0; g < 4; ++g) {
      us4 pa, pb;
#pragma unroll
      for (int jj = 0; jj < 4; ++jj) {
        pa[jj] = f2bf(oA[4 * g + jj] * inv);
        pb[jj] = f2bf(oB[4 * g + jj] * inv);
      }
      *reinterpret_cast<us4*>(&att[obase + g * 8 + 4 * hi]) = pa;
      *reinterpret_cast<us4*>(&att[obase + 32 + g * 8 + 4 * hi]) = pb;
    }
  };

  run_pos(63 - p);  // heavy half first (streams K/V, warms L2 for light half)
  run_pos(p);       // light half re-reads an L2-hot prefix
}

extern "C" void kernel_launch(void* const* d_in, const int* in_sizes, int n_in,
                              void* d_out, int out_size, void* d_ws, size_t ws_size,
                              hipStream_t stream) {
  const float* x = (const float*)d_in[0];
  const float* Wq = (const float*)d_in[1];
  const float* Wkv = (const float*)d_in[2];
  const float* Wc = (const float*)d_in[3];
  float* out = (float*)d_out;

  char* ws = (char*)d_ws;
  size_t off = 0;
  auto alloc = [&](size_t bytes) {
    void* p = ws + off;
    off += (bytes + 255) & ~(size_t)255;
    return p;
  };
  const size_t NTOK = 4ull * T_SEQ;            // 8192
  const size_t NELEM = NTOK * CDIM;            // 8388608
  unsigned short* xb = (unsigned short*)alloc(NELEM * 2);   // also reused for att
  unsigned short* WT = (unsigned short*)alloc(3072ull * 1024 * 2);
  unsigned short* WcT = (unsigned short*)alloc(1024ull * 1024 * 2);
  unsigned short* qb = (unsigned short*)alloc(NELEM * 2);
  unsigned short* kb = (unsigned short*)alloc(NELEM * 2);
  unsigned short* vT = (unsigned short*)alloc(NELEM * 2);
  float* cost = (float*)alloc(T_SEQ * 32 * 4);
  float* sint = (float*)alloc(T_SEQ * 32 * 4);
  unsigned short* att = xb;  // xb dead after gemm<1>; reuse for attention output

  cast_x_kernel<<<(int)(NELEM / 4 / 256), 256, 0, stream>>>(x, xb, (int)(NELEM / 4));
  transpose_cast_kernel<<<dim3(32, 32), dim3(32, 8), 0, stream>>>(Wq, WT, 1024, 1024);
  transpose_cast_kernel<<<dim3(64, 32), dim3(32, 8), 0, stream>>>(Wkv, WT + 1024 * 1024, 2048,
                                                                  1024);
  transpose_cast_kernel<<<dim3(32, 32), dim3(32, 8), 0, stream>>>(Wc, WcT, 1024, 1024);
  rope_table_kernel<<<T_SEQ * 32 / 256, 256, 0, stream>>>(cost, sint);

  gemm_kernel<1><<<dim3(3072 / 128, NTOK / 128), 256, 0, stream>>>(
      xb, WT, (int)NTOK, 3072, 1024, qb, kb, vT, cost, sint, nullptr);

  attn_kernel<<<dim3(512), 256, 0, stream>>>(qb, kb, vT, att);

  gemm_kernel<0><<<dim3(1024 / 128, NTOK / 128), 256, 0, stream>>>(
      att, WcT, (int)NTOK, 1024, 1024, nullptr, nullptr, nullptr, nullptr, nullptr, out);
}

// Round 12
// 174.249 us; speedup vs baseline: 1.1323x; 1.0174x over previous
//
#include <hip/hip_runtime.h>
#include <math.h>

typedef __attribute__((ext_vector_type(4))) float f32x4;
typedef __attribute__((ext_vector_type(16))) float f32x16;
typedef __attribute__((ext_vector_type(8))) short bf16x8;
typedef __attribute__((ext_vector_type(4))) unsigned short us4;
typedef __attribute__((ext_vector_type(4))) unsigned int u32x4;

#define T_SEQ 2048
#define NH 16
#define HD 64
#define CDIM 1024

__device__ __forceinline__ unsigned short f2bf(float f) {
  unsigned int u = __float_as_uint(f);
  u += 0x7fffu + ((u >> 16) & 1u);
  return (unsigned short)(u >> 16);
}

__device__ __forceinline__ f32x16 zero16() {
  f32x16 z;
#pragma unroll
  for (int i = 0; i < 16; ++i) z[i] = 0.0f;
  return z;
}

// global -> LDS direct (16B/lane, wave-uniform LDS base + lane*16)
#define GLOAD_LDS(g, l)                                                   \
  __builtin_amdgcn_global_load_lds(                                       \
      (const __attribute__((address_space(1))) unsigned int*)(g),         \
      (__attribute__((address_space(3))) unsigned int*)(l), 16, 0, 0)

// ---------------- cast x: fp32 -> bf16 ----------------
__global__ __launch_bounds__(256) void cast_x_kernel(const float* __restrict__ src,
                                                     unsigned short* __restrict__ dst,
                                                     int n4) {
  int i = blockIdx.x * 256 + threadIdx.x;
  if (i >= n4) return;
  f32x4 v = reinterpret_cast<const f32x4*>(src)[i];
  us4 o;
#pragma unroll
  for (int j = 0; j < 4; ++j) o[j] = f2bf(v[j]);
  reinterpret_cast<us4*>(dst)[i] = o;
}

// ------------- transpose + cast: W [K][N] fp32 -> W^T [N][K] bf16 -------------
__global__ __launch_bounds__(256) void transpose_cast_kernel(const float* __restrict__ src,
                                                             unsigned short* __restrict__ dst,
                                                             int ldsrc, int lddst) {
  __shared__ float tile[32][33];
  int n0 = blockIdx.x * 32, k0 = blockIdx.y * 32;
  int tx = threadIdx.x, ty = threadIdx.y;  // block (32,8)
#pragma unroll
  for (int r = 0; r < 4; ++r)
    tile[ty + r * 8][tx] = src[(size_t)(k0 + ty + r * 8) * ldsrc + n0 + tx];
  __syncthreads();
#pragma unroll
  for (int r = 0; r < 4; ++r)
    dst[(size_t)(n0 + ty + r * 8) * lddst + k0 + tx] = f2bf(tile[tx][ty + r * 8]);
}

// ---------------- RoPE table: cos/sin [T][32] fp32 ----------------
__global__ __launch_bounds__(256) void rope_table_kernel(float* __restrict__ cost,
                                                         float* __restrict__ sint) {
  int idx = blockIdx.x * 256 + threadIdx.x;  // 2048*32
  int t = idx >> 5, j = idx & 31;
  double invf = pow(10000.0, -(double)j / 32.0);
  double ang = (double)t * invf;
  cost[idx] = (float)cos(ang);
  sint[idx] = (float)sin(ang);
}

// ---------------- GEMM: C[M][N] = A[M][K] * B^T[N][K], bf16 in, fp32 acc ----
// 2-phase double-buffered pipeline (R9, attested 682 TF): STAGE next K-tile
// via global_load_lds BEFORE computing current tile; ONE __syncthreads per
// tile. BK=64, 2x32KB LDS. XOR col-block swizzle both-sides (rule 21) ->
// 0 bank conflicts (verified R8). T4 counted-vmcnt graft REGRESSED (R10,
// -28%): do not re-add without the full 8-phase interleave.
// MODE 1: qkv epilogue with RoPE, fragment-major outputs
//   QF/KF[bh][blk32][ks][lane][8], VF[bh][t64][dgrp][ks][lane][8].
// MODE 0: plain fp32 store to out[M][N].
template <int MODE>
__global__ __launch_bounds__(256) void gemm_kernel(
    const unsigned short* __restrict__ A, const unsigned short* __restrict__ Bt,
    int M, int N, int K,
    unsigned short* __restrict__ qo, unsigned short* __restrict__ ko,
    unsigned short* __restrict__ vTo, const float* __restrict__ cost,
    const float* __restrict__ sint, float* __restrict__ out) {
  __shared__ __align__(16) unsigned short As[2][128 * 64];  // 2 x 16KB
  __shared__ __align__(16) unsigned short Bs[2][128 * 64];  // 2 x 16KB
  const int tid = threadIdx.x;
  const int lane = tid & 63;
  const int wave = tid >> 6;
  const int wr = wave >> 1, wc = wave & 1;
  const int m0 = blockIdx.y * 128, n0 = blockIdx.x * 128;
  const int lrow = lane & 15, lhi = lane >> 4;
  const int srow = lane >> 3;                  // row within 8-row chunk
  const int scol = (((lane & 7) ^ srow) * 8);  // swizzled source col (elems)

  f32x4 zero4 = {0.f, 0.f, 0.f, 0.f};
  f32x4 acc[4][4];
#pragma unroll
  for (int mi = 0; mi < 4; ++mi)
#pragma unroll
    for (int ni = 0; ni < 4; ++ni) acc[mi][ni] = zero4;

  const int ntiles = K >> 6;  // BK=64
  auto stage = [&](int bf, int kt) {
#pragma unroll
    for (int c2 = 0; c2 < 4; ++c2) {
      const int c = wave * 4 + c2;  // chunk 0..15 (8 rows x 128B each)
      GLOAD_LDS(&A[(size_t)(m0 + c * 8 + srow) * K + kt + scol], &As[bf][c * 512]);
      GLOAD_LDS(&Bt[(size_t)(n0 + c * 8 + srow) * K + kt + scol], &Bs[bf][c * 512]);
    }
  };

  stage(0, 0);
  __syncthreads();  // buf0 ready
  int cur = 0;
  for (int ti = 0; ti < ntiles; ++ti) {
    if (ti + 1 < ntiles) stage(cur ^ 1, (ti + 1) * 64);  // in flight under compute
#pragma unroll
    for (int kk = 0; kk < 2; ++kk) {
      bf16x8 af[4], bfv[4];
#pragma unroll
      for (int i = 0; i < 4; ++i) {
        const int ra = wr * 64 + i * 16 + lrow;
        const int rb = wc * 64 + i * 16 + lrow;
        const int cba = (kk * 4 + lhi) ^ (ra & 7);  // un-swizzle on read
        const int cbb = (kk * 4 + lhi) ^ (rb & 7);
        af[i] = *reinterpret_cast<const bf16x8*>(&As[cur][ra * 64 + cba * 8]);
        bfv[i] = *reinterpret_cast<const bf16x8*>(&Bs[cur][rb * 64 + cbb * 8]);
      }
#pragma unroll
      for (int mi = 0; mi < 4; ++mi)
#pragma unroll
        for (int ni = 0; ni < 4; ++ni)
          acc[mi][ni] =
              __builtin_amdgcn_mfma_f32_16x16x32_bf16(af[mi], bfv[ni], acc[mi][ni], 0, 0, 0);
    }
    __syncthreads();  // drains my gloads (flew under MFMA) + reads; swap safe
    cur ^= 1;
  }

  if (MODE == 0) {
#pragma unroll
    for (int mi = 0; mi < 4; ++mi)
#pragma unroll
      for (int ni = 0; ni < 4; ++ni) {
        int n = n0 + wc * 64 + ni * 16 + lrow;
#pragma unroll
        for (int r = 0; r < 4; ++r) {
          int m = m0 + wr * 64 + mi * 16 + lhi * 4 + r;
          out[(size_t)m * N + n] = acc[mi][ni][r];
        }
      }
  } else {
#pragma unroll
    for (int mi = 0; mi < 4; ++mi) {
      int mb = m0 + wr * 64 + mi * 16 + lhi * 4;  // 4 consecutive rows (t)
      int b = mb >> 11, tb = mb & (T_SEQ - 1);
#pragma unroll
      for (int ni = 0; ni < 4; ++ni) {
        int n = n0 + wc * 64 + ni * 16 + lrow;
        int sec = n >> 10;          // 0=q 1=k 2=v
        int h = (n >> 6) & 15;
        int d = n & 63;
        int bh_ = b * NH + h;
        if (sec == 2) {
          int t64 = tb >> 6, ks = (tb >> 4) & 3, hiv = (tb >> 3) & 1, e0 = tb & 7;
          int dgrp = d >> 5, lanev = hiv * 32 + (d & 31);
          us4 pk;
#pragma unroll
          for (int r = 0; r < 4; ++r) pk[r] = f2bf(acc[mi][ni][r]);
          size_t addr =
              ((((size_t)bh_ * 32 + t64) * 2 + dgrp) * 4 + ks) * 512 + lanev * 8 + e0;
          *reinterpret_cast<us4*>(&vTo[addr]) = pk;
        } else {
          int dm = d & 31;
          float sgn = (d < 32) ? -1.0f : 1.0f;
          unsigned short* dstp = (sec == 0) ? qo : ko;
          int ks = d >> 4, hiq = (d >> 3) & 1, e = d & 7;
#pragma unroll
          for (int r = 0; r < 4; ++r) {
            int t = tb + r;
            float c = cost[t * 32 + dm], s = sint[t * 32 + dm];
            float val = acc[mi][ni][r] * c + sgn * acc[mi][ni ^ 2][r] * s;
            if (sec == 0) val *= 0.125f;  // 1/sqrt(64) folded into q
            int blk = t >> 5, lane_ = hiq * 32 + (t & 31);
            dstp[(((size_t)bh_ * 64 + blk) * 4 + ks) * 512 + lane_ * 8 + e] = f2bf(val);
          }
        }
      }
    }
  }
}

// ---------------- flash attention, causal; 32x32 swapped-QK^T ----------------
// EXACT per-wave balance: wave owns q-blocks {p, 63-p} (33 kv-tiles each).
// 512 blocks (2/CU, 8 waves/CU). Register double-buffered K AND V prefetch.
// T12 (this round): P -> PV B-fragments built fully in registers via
// v_cvt_pk_bf16_f32 (16) + v_permlane32_swap_b32 (8); replaces 32x manual
// f2bf + per-wave LDS roundtrip. Derivation (verified vs m214 r272 layout):
// key(r,hi) = (r&3)+8*(r>>2)+4*hi; u_m=cvtpk(s[4m],s[4m+1]),
// v_m=cvtpk(s[4m+2],s[4m+3]); swap(u_2t,u_2t+1) -> word0(own)/word2(partner)
// of B-frag slice t. Kernel now uses ZERO LDS. T13 defer-max; setprio.
__global__ __launch_bounds__(256, 2) void attn_kernel(const unsigned short* __restrict__ qg,
                                                      const unsigned short* __restrict__ kg,
                                                      const unsigned short* __restrict__ vtg,
                                                      unsigned short* __restrict__ att) {
  const int tid = threadIdx.x;
  const int lane = tid & 63;
  const int w = tid >> 6;
  const int l31 = lane & 31, hi = lane >> 5;
  const int bid = (int)blockIdx.x;
  const int xcd = bid & 7, j = bid >> 3;        // j 0..63
  const int bh = xcd * 8 + (j >> 3);            // 8 blocks per head
  const int p = (j & 7) * 4 + w;                // pair index 0..31
  const unsigned short* qfp = qg + (size_t)bh * 131072;
  const unsigned short* kfp = kg + (size_t)bh * 131072;
  const unsigned short* vfp = vtg + (size_t)bh * 131072;
  const int b = bh >> 4, h = bh & 15;

  auto run_pos = [&](int pos) {
    const int qrow = pos * 32 + l31;
    bf16x8 qf[4];
#pragma unroll
    for (int ks = 0; ks < 4; ++ks)
      qf[ks] =
          *reinterpret_cast<const bf16x8*>(&qfp[((size_t)pos * 4 + ks) * 512 + lane * 8]);
    f32x16 oA = zero16(), oB = zero16();
    float mrun = -3.0e38f, lrun = 0.0f;
    const int myt = (pos >> 1) + 1;

    bf16x8 kA0[4], kB0[4], kA1[4], kB1[4];
    bf16x8 vA0[4], vB0[4], vA1[4], vB1[4];
#pragma unroll
    for (int ks = 0; ks < 4; ++ks) {  // preload K+V tile 0
      kA0[ks] = *reinterpret_cast<const bf16x8*>(&kfp[(size_t)(0 + ks) * 512 + lane * 8]);
      kB0[ks] = *reinterpret_cast<const bf16x8*>(&kfp[(size_t)(4 + ks) * 512 + lane * 8]);
      vA0[ks] = *reinterpret_cast<const bf16x8*>(&vfp[(size_t)(0 + ks) * 512 + lane * 8]);
      vB0[ks] = *reinterpret_cast<const bf16x8*>(&vfp[(size_t)(4 + ks) * 512 + lane * 8]);
    }

    auto step = [&](int t, bf16x8 (&kcA)[4], bf16x8 (&kcB)[4], bf16x8 (&knA)[4],
                    bf16x8 (&knB)[4], bf16x8 (&vcA)[4], bf16x8 (&vcB)[4],
                    bf16x8 (&vnA)[4], bf16x8 (&vnB)[4]) {
      // QK^T with current K (prefetched last iteration)
      f32x16 sA = zero16(), sB = zero16();
      __builtin_amdgcn_s_setprio(1);
#pragma unroll
      for (int ks = 0; ks < 4; ++ks) {
        sA = __builtin_amdgcn_mfma_f32_32x32x16_bf16(kcA[ks], qf[ks], sA, 0, 0, 0);
        sB = __builtin_amdgcn_mfma_f32_32x32x16_bf16(kcB[ks], qf[ks], sB, 0, 0, 0);
      }
      __builtin_amdgcn_s_setprio(0);
      // prefetch next K AND V tiles (consumed next iteration)
      if (t + 1 < myt) {
#pragma unroll
        for (int ks = 0; ks < 4; ++ks) {
          knA[ks] = *reinterpret_cast<const bf16x8*>(
              &kfp[((size_t)(2 * t + 2) * 4 + ks) * 512 + lane * 8]);
          knB[ks] = *reinterpret_cast<const bf16x8*>(
              &kfp[((size_t)(2 * t + 3) * 4 + ks) * 512 + lane * 8]);
          vnA[ks] = *reinterpret_cast<const bf16x8*>(
              &vfp[((size_t)(2 * t + 2) * 4 + ks) * 512 + lane * 8]);
          vnB[ks] = *reinterpret_cast<const bf16x8*>(
              &vfp[((size_t)(2 * t + 3) * 4 + ks) * 512 + lane * 8]);
        }
      }
      // causal mask (only final tile can contain future keys)
      if (t == myt - 1) {
        const int kvb = t * 64;
#pragma unroll
        for (int r = 0; r < 16; ++r) {
          int keyA = kvb + (r & 3) + 8 * (r >> 2) + 4 * hi;
          if (keyA > qrow) sA[r] = -1e30f;
          if (keyA + 32 > qrow) sB[r] = -1e30f;
        }
      }
      // in-register online softmax (per-lane scalars)
      float tr[16];
#pragma unroll
      for (int i = 0; i < 16; ++i) tr[i] = fmaxf(sA[i], sB[i]);
#pragma unroll
      for (int i = 0; i < 8; ++i) tr[i] = fmaxf(tr[i], tr[i + 8]);
#pragma unroll
      for (int i = 0; i < 4; ++i) tr[i] = fmaxf(tr[i], tr[i + 4]);
      float tm = fmaxf(fmaxf(tr[0], tr[1]), fmaxf(tr[2], tr[3]));
      tm = fmaxf(tm, __shfl_xor(tm, 32));  // merge lane halves (same query)
      // T13 defer-max: only rescale when max grew by > 8
      if (!__all(tm - mrun <= 8.0f)) {
        float mnew = fmaxf(mrun, tm);
        float alpha = __expf(mrun - mnew);
        lrun *= alpha;
#pragma unroll
        for (int i = 0; i < 16; ++i) {
          oA[i] *= alpha;
          oB[i] *= alpha;
        }
        mrun = mnew;
      }
#pragma unroll
      for (int i = 0; i < 16; ++i) {
        sA[i] = __expf(sA[i] - mrun);
        sB[i] = __expf(sB[i] - mrun);
      }
      float sr[16];
#pragma unroll
      for (int i = 0; i < 16; ++i) sr[i] = sA[i] + sB[i];
#pragma unroll
      for (int i = 0; i < 8; ++i) sr[i] += sr[i + 8];
#pragma unroll
      for (int i = 0; i < 4; ++i) sr[i] += sr[i + 4];
      float lsum = (sr[0] + sr[1]) + (sr[2] + sr[3]);
      lsum += __shfl_xor(lsum, 32);
      lrun += lsum;
      // T12: P -> B-operand fragments in registers (cvt_pk + permlane32_swap)
      unsigned int ua[4], va[4], ub[4], vb[4];
#pragma unroll
      for (int m = 0; m < 4; ++m) {
        asm("v_cvt_pk_bf16_f32 %0, %1, %2" : "=v"(ua[m]) : "v"(sA[4 * m]), "v"(sA[4 * m + 1]));
        asm("v_cvt_pk_bf16_f32 %0, %1, %2" : "=v"(va[m]) : "v"(sA[4 * m + 2]), "v"(sA[4 * m + 3]));
        asm("v_cvt_pk_bf16_f32 %0, %1, %2" : "=v"(ub[m]) : "v"(sB[4 * m]), "v"(sB[4 * m + 1]));
        asm("v_cvt_pk_bf16_f32 %0, %1, %2" : "=v"(vb[m]) : "v"(sB[4 * m + 2]), "v"(sB[4 * m + 3]));
      }
      asm("v_permlane32_swap_b32 %0, %1" : "+v"(ua[0]), "+v"(ua[1]));
      asm("v_permlane32_swap_b32 %0, %1" : "+v"(va[0]), "+v"(va[1]));
      asm("v_permlane32_swap_b32 %0, %1" : "+v"(ua[2]), "+v"(ua[3]));
      asm("v_permlane32_swap_b32 %0, %1" : "+v"(va[2]), "+v"(va[3]));
      asm("v_permlane32_swap_b32 %0, %1" : "+v"(ub[0]), "+v"(ub[1]));
      asm("v_permlane32_swap_b32 %0, %1" : "+v"(vb[0]), "+v"(vb[1]));
      asm("v_permlane32_swap_b32 %0, %1" : "+v"(ub[2]), "+v"(ub[3]));
      asm("v_permlane32_swap_b32 %0, %1" : "+v"(vb[2]), "+v"(vb[3]));
      u32x4 w0 = {ua[0], va[0], ua[1], va[1]};  // slice 0: keys 0-15
      u32x4 w1 = {ua[2], va[2], ua[3], va[3]};  // slice 1: keys 16-31
      u32x4 w2 = {ub[0], vb[0], ub[1], vb[1]};  // slice 2: keys 32-47
      u32x4 w3 = {ub[2], vb[2], ub[3], vb[3]};  // slice 3: keys 48-63
      bf16x8 pf0 = __builtin_bit_cast(bf16x8, w0);
      bf16x8 pf1 = __builtin_bit_cast(bf16x8, w1);
      bf16x8 pf2 = __builtin_bit_cast(bf16x8, w2);
      bf16x8 pf3 = __builtin_bit_cast(bf16x8, w3);
      // PV: O^T += mfma(V^T, P)
      __builtin_amdgcn_s_setprio(1);
      oA = __builtin_amdgcn_mfma_f32_32x32x16_bf16(vcA[0], pf0, oA, 0, 0, 0);
      oB = __builtin_amdgcn_mfma_f32_32x32x16_bf16(vcB[0], pf0, oB, 0, 0, 0);
      oA = __builtin_amdgcn_mfma_f32_32x32x16_bf16(vcA[1], pf1, oA, 0, 0, 0);
      oB = __builtin_amdgcn_mfma_f32_32x32x16_bf16(vcB[1], pf1, oB, 0, 0, 0);
      oA = __builtin_amdgcn_mfma_f32_32x32x16_bf16(vcA[2], pf2, oA, 0, 0, 0);
      oB = __builtin_amdgcn_mfma_f32_32x32x16_bf16(vcB[2], pf2, oB, 0, 0, 0);
      oA = __builtin_amdgcn_mfma_f32_32x32x16_bf16(vcA[3], pf3, oA, 0, 0, 0);
      oB = __builtin_amdgcn_mfma_f32_32x32x16_bf16(vcB[3], pf3, oB, 0, 0, 0);
      __builtin_amdgcn_s_setprio(0);
    };

    int t = 0;
    while (t < myt) {
      step(t, kA0, kB0, kA1, kB1, vA0, vB0, vA1, vB1);
      ++t;
      if (t >= myt) break;
      step(t, kA1, kB1, kA0, kB0, vA1, vB1, vA0, vB0);
      ++t;
    }

    const float inv = 1.0f / lrun;
    const size_t obase = ((size_t)b * T_SEQ + qrow) * CDIM + h * HD;
#pragma unroll
    for (int g = 0; g < 4; ++g) {
      us4 pa, pb;
#pragma unroll
      for (int jj = 0; jj < 4; ++jj) {
        pa[jj] = f2bf(oA[4 * g + jj] * inv);
        pb[jj] = f2bf(oB[4 * g + jj] * inv);
      }
      *reinterpret_cast<us4*>(&att[obase + g * 8 + 4 * hi]) = pa;
      *reinterpret_cast<us4*>(&att[obase + 32 + g * 8 + 4 * hi]) = pb;
    }
  };

  run_pos(63 - p);  // heavy half first (streams K/V, warms L2 for light half)
  run_pos(p);       // light half re-reads an L2-hot prefix
}

extern "C" void kernel_launch(void* const* d_in, const int* in_sizes, int n_in,
                              void* d_out, int out_size, void* d_ws, size_t ws_size,
                              hipStream_t stream) {
  const float* x = (const float*)d_in[0];
  const float* Wq = (const float*)d_in[1];
  const float* Wkv = (const float*)d_in[2];
  const float* Wc = (const float*)d_in[3];
  float* out = (float*)d_out;

  char* ws = (char*)d_ws;
  size_t off = 0;
  auto alloc = [&](size_t bytes) {
    void* p = ws + off;
    off += (bytes + 255) & ~(size_t)255;
    return p;
  };
  const size_t NTOK = 4ull * T_SEQ;            // 8192
  const size_t NELEM = NTOK * CDIM;            // 8388608
  unsigned short* xb = (unsigned short*)alloc(NELEM * 2);   // also reused for att
  unsigned short* WT = (unsigned short*)alloc(3072ull * 1024 * 2);
  unsigned short* WcT = (unsigned short*)alloc(1024ull * 1024 * 2);
  unsigned short* qb = (unsigned short*)alloc(NELEM * 2);
  unsigned short* kb = (unsigned short*)alloc(NELEM * 2);
  unsigned short* vT = (unsigned short*)alloc(NELEM * 2);
  float* cost = (float*)alloc(T_SEQ * 32 * 4);
  float* sint = (float*)alloc(T_SEQ * 32 * 4);
  unsigned short* att = xb;  // xb dead after gemm<1>; reuse for attention output

  cast_x_kernel<<<(int)(NELEM / 4 / 256), 256, 0, stream>>>(x, xb, (int)(NELEM / 4));
  transpose_cast_kernel<<<dim3(32, 32), dim3(32, 8), 0, stream>>>(Wq, WT, 1024, 1024);
  transpose_cast_kernel<<<dim3(64, 32), dim3(32, 8), 0, stream>>>(Wkv, WT + 1024 * 1024, 2048,
                                                                  1024);
  transpose_cast_kernel<<<dim3(32, 32), dim3(32, 8), 0, stream>>>(Wc, WcT, 1024, 1024);
  rope_table_kernel<<<T_SEQ * 32 / 256, 256, 0, stream>>>(cost, sint);

  gemm_kernel<1><<<dim3(3072 / 128, NTOK / 128), 256, 0, stream>>>(
      xb, WT, (int)NTOK, 3072, 1024, qb, kb, vT, cost, sint, nullptr);

  attn_kernel<<<dim3(512), 256, 0, stream>>>(qb, kb, vT, att);

  gemm_kernel<0><<<dim3(1024 / 128, NTOK / 128), 256, 0, stream>>>(
      att, WcT, (int)NTOK, 1024, 1024, nullptr, nullptr, nullptr, nullptr, nullptr, out);
}

// Round 13
// 170.365 us; speedup vs baseline: 1.1582x; 1.0228x over previous
//
#include <hip/hip_runtime.h>
#include <math.h>

typedef __attribute__((ext_vector_type(4))) float f32x4;
typedef __attribute__((ext_vector_type(16))) float f32x16;
typedef __attribute__((ext_vector_type(8))) short bf16x8;
typedef __attribute__((ext_vector_type(4))) unsigned short us4;
typedef __attribute__((ext_vector_type(4))) unsigned int u32x4;

#define T_SEQ 2048
#define NH 16
#define HD 64
#define CDIM 1024

__device__ __forceinline__ unsigned short f2bf(float f) {
  unsigned int u = __float_as_uint(f);
  u += 0x7fffu + ((u >> 16) & 1u);
  return (unsigned short)(u >> 16);
}

__device__ __forceinline__ f32x16 zero16() {
  f32x16 z;
#pragma unroll
  for (int i = 0; i < 16; ++i) z[i] = 0.0f;
  return z;
}

// global -> LDS direct (16B/lane, wave-uniform LDS base + lane*16)
#define GLOAD_LDS(g, l)                                                   \
  __builtin_amdgcn_global_load_lds(                                       \
      (const __attribute__((address_space(1))) unsigned int*)(g),         \
      (__attribute__((address_space(3))) unsigned int*)(l), 16, 0, 0)

// ---------------- cast x: fp32 -> bf16 ----------------
__global__ __launch_bounds__(256) void cast_x_kernel(const float* __restrict__ src,
                                                     unsigned short* __restrict__ dst,
                                                     int n4) {
  int i = blockIdx.x * 256 + threadIdx.x;
  if (i >= n4) return;
  f32x4 v = reinterpret_cast<const f32x4*>(src)[i];
  us4 o;
#pragma unroll
  for (int j = 0; j < 4; ++j) o[j] = f2bf(v[j]);
  reinterpret_cast<us4*>(dst)[i] = o;
}

// ------------- transpose + cast: W [K][N] fp32 -> W^T [N][K] bf16 -------------
__global__ __launch_bounds__(256) void transpose_cast_kernel(const float* __restrict__ src,
                                                             unsigned short* __restrict__ dst,
                                                             int ldsrc, int lddst) {
  __shared__ float tile[32][33];
  int n0 = blockIdx.x * 32, k0 = blockIdx.y * 32;
  int tx = threadIdx.x, ty = threadIdx.y;  // block (32,8)
#pragma unroll
  for (int r = 0; r < 4; ++r)
    tile[ty + r * 8][tx] = src[(size_t)(k0 + ty + r * 8) * ldsrc + n0 + tx];
  __syncthreads();
#pragma unroll
  for (int r = 0; r < 4; ++r)
    dst[(size_t)(n0 + ty + r * 8) * lddst + k0 + tx] = f2bf(tile[tx][ty + r * 8]);
}

// ---------------- RoPE table: cos/sin [T][32] fp32 ----------------
__global__ __launch_bounds__(256) void rope_table_kernel(float* __restrict__ cost,
                                                         float* __restrict__ sint) {
  int idx = blockIdx.x * 256 + threadIdx.x;  // 2048*32
  int t = idx >> 5, j = idx & 31;
  double invf = pow(10000.0, -(double)j / 32.0);
  double ang = (double)t * invf;
  cost[idx] = (float)cos(ang);
  sint[idx] = (float)sin(ang);
}

// ---------------- GEMM: C[M][N] = A[M][K] * B^T[N][K], bf16 in, fp32 acc ----
// 2-phase double-buffered pipeline (R9, attested 682 TF). BK=64, 2x32KB LDS.
// XOR col-block swizzle both-sides (rule 21) -> 0 bank conflicts (R8).
// T4 counted-vmcnt graft REGRESSED (R10): don't re-add without full 8-phase.
template <int MODE>
__global__ __launch_bounds__(256) void gemm_kernel(
    const unsigned short* __restrict__ A, const unsigned short* __restrict__ Bt,
    int M, int N, int K,
    unsigned short* __restrict__ qo, unsigned short* __restrict__ ko,
    unsigned short* __restrict__ vTo, const float* __restrict__ cost,
    const float* __restrict__ sint, float* __restrict__ out) {
  __shared__ __align__(16) unsigned short As[2][128 * 64];  // 2 x 16KB
  __shared__ __align__(16) unsigned short Bs[2][128 * 64];  // 2 x 16KB
  const int tid = threadIdx.x;
  const int lane = tid & 63;
  const int wave = tid >> 6;
  const int wr = wave >> 1, wc = wave & 1;
  const int m0 = blockIdx.y * 128, n0 = blockIdx.x * 128;
  const int lrow = lane & 15, lhi = lane >> 4;
  const int srow = lane >> 3;                  // row within 8-row chunk
  const int scol = (((lane & 7) ^ srow) * 8);  // swizzled source col (elems)

  f32x4 zero4 = {0.f, 0.f, 0.f, 0.f};
  f32x4 acc[4][4];
#pragma unroll
  for (int mi = 0; mi < 4; ++mi)
#pragma unroll
    for (int ni = 0; ni < 4; ++ni) acc[mi][ni] = zero4;

  const int ntiles = K >> 6;  // BK=64
  auto stage = [&](int bf, int kt) {
#pragma unroll
    for (int c2 = 0; c2 < 4; ++c2) {
      const int c = wave * 4 + c2;  // chunk 0..15 (8 rows x 128B each)
      GLOAD_LDS(&A[(size_t)(m0 + c * 8 + srow) * K + kt + scol], &As[bf][c * 512]);
      GLOAD_LDS(&Bt[(size_t)(n0 + c * 8 + srow) * K + kt + scol], &Bs[bf][c * 512]);
    }
  };

  stage(0, 0);
  __syncthreads();  // buf0 ready
  int cur = 0;
  for (int ti = 0; ti < ntiles; ++ti) {
    if (ti + 1 < ntiles) stage(cur ^ 1, (ti + 1) * 64);  // in flight under compute
#pragma unroll
    for (int kk = 0; kk < 2; ++kk) {
      bf16x8 af[4], bfv[4];
#pragma unroll
      for (int i = 0; i < 4; ++i) {
        const int ra = wr * 64 + i * 16 + lrow;
        const int rb = wc * 64 + i * 16 + lrow;
        const int cba = (kk * 4 + lhi) ^ (ra & 7);  // un-swizzle on read
        const int cbb = (kk * 4 + lhi) ^ (rb & 7);
        af[i] = *reinterpret_cast<const bf16x8*>(&As[cur][ra * 64 + cba * 8]);
        bfv[i] = *reinterpret_cast<const bf16x8*>(&Bs[cur][rb * 64 + cbb * 8]);
      }
#pragma unroll
      for (int mi = 0; mi < 4; ++mi)
#pragma unroll
        for (int ni = 0; ni < 4; ++ni)
          acc[mi][ni] =
              __builtin_amdgcn_mfma_f32_16x16x32_bf16(af[mi], bfv[ni], acc[mi][ni], 0, 0, 0);
    }
    __syncthreads();  // drains my gloads (flew under MFMA) + reads; swap safe
    cur ^= 1;
  }

  if (MODE == 0) {
#pragma unroll
    for (int mi = 0; mi < 4; ++mi)
#pragma unroll
      for (int ni = 0; ni < 4; ++ni) {
        int n = n0 + wc * 64 + ni * 16 + lrow;
#pragma unroll
        for (int r = 0; r < 4; ++r) {
          int m = m0 + wr * 64 + mi * 16 + lhi * 4 + r;
          out[(size_t)m * N + n] = acc[mi][ni][r];
        }
      }
  } else {
#pragma unroll
    for (int mi = 0; mi < 4; ++mi) {
      int mb = m0 + wr * 64 + mi * 16 + lhi * 4;  // 4 consecutive rows (t)
      int b = mb >> 11, tb = mb & (T_SEQ - 1);
#pragma unroll
      for (int ni = 0; ni < 4; ++ni) {
        int n = n0 + wc * 64 + ni * 16 + lrow;
        int sec = n >> 10;          // 0=q 1=k 2=v
        int h = (n >> 6) & 15;
        int d = n & 63;
        int bh_ = b * NH + h;
        if (sec == 2) {
          int t64 = tb >> 6, ks = (tb >> 4) & 3, hiv = (tb >> 3) & 1, e0 = tb & 7;
          int dgrp = d >> 5, lanev = hiv * 32 + (d & 31);
          us4 pk;
#pragma unroll
          for (int r = 0; r < 4; ++r) pk[r] = f2bf(acc[mi][ni][r]);
          size_t addr =
              ((((size_t)bh_ * 32 + t64) * 2 + dgrp) * 4 + ks) * 512 + lanev * 8 + e0;
          *reinterpret_cast<us4*>(&vTo[addr]) = pk;
        } else {
          int dm = d & 31;
          float sgn = (d < 32) ? -1.0f : 1.0f;
          unsigned short* dstp = (sec == 0) ? qo : ko;
          int ks = d >> 4, hiq = (d >> 3) & 1, e = d & 7;
#pragma unroll
          for (int r = 0; r < 4; ++r) {
            int t = tb + r;
            float c = cost[t * 32 + dm], s = sint[t * 32 + dm];
            float val = acc[mi][ni][r] * c + sgn * acc[mi][ni ^ 2][r] * s;
            if (sec == 0) val *= 0.125f;  // 1/sqrt(64) folded into q
            int blk = t >> 5, lane_ = hiq * 32 + (t & 31);
            dstp[(((size_t)bh_ * 64 + blk) * 4 + ks) * 512 + lane_ * 8 + e] = f2bf(val);
          }
        }
      }
    }
  }
}

// ---------------- flash attention, causal; 32x32 swapped-QK^T ----------------
// 8-wave / 512-thread blocks; K/V tile (16KB, contiguous fragment-major)
// staged ONCE per block into double-buffered LDS via global_load_lds (R9's
// proven 2-phase recipe: issue buf^1 BEFORE compute, one barrier per tile).
// Cuts attn L2 traffic 8x (1.08GB -> 210MB) and moves operand reads to LDS
// (128 B/cyc/CU vs 56 B/cyc/CU L2 share) -- the measured per-tile wall.
// Block i owns q-positions {4i..4i+3} U {63-4i..60-4i}; lockstep maxT=32-2i;
// blocks bid and bid+256 (same CU under round-robin) get complementary i ->
// equal 50 steps per CU (perf heuristic only). In-register softmax; T13
// defer-max; T12 cvt_pk+permlane P-pack; setprio around MFMA.
__global__ __launch_bounds__(512, 2) void attn_kernel(const unsigned short* __restrict__ qg,
                                                      const unsigned short* __restrict__ kg,
                                                      const unsigned short* __restrict__ vtg,
                                                      unsigned short* __restrict__ att) {
  __shared__ __align__(16) unsigned short Ks[2][4096];  // 2 x 8KB (64 keys x 64 d)
  __shared__ __align__(16) unsigned short Vs[2][4096];  // 2 x 8KB
  const int tid = threadIdx.x;
  const int lane = tid & 63;
  const int w = tid >> 6;
  const int l31 = lane & 31, hi = lane >> 5;
  const int bid = (int)blockIdx.x;          // 0..511
  const int second = bid >> 8;              // 0: first 256 (one/CU), 1: second
  const int q = bid & 255;
  const int xcd = q & 7, g = q >> 3;        // g 0..31
  const int bh = xcd * 8 + (g >> 2);        // 8 heads per xcd
  const int ii = g & 3;
  const int i = second ? (7 - ii) : ii;     // complementary i on same CU
  const int pos = (w < 4) ? (4 * i + w) : (63 - 4 * i - (w - 4));
  const int qrow = pos * 32 + l31;
  const int myt = (pos >> 1) + 1;
  const int maxT = 32 - 2 * i;              // = myt(63-4i)
  const unsigned short* qfp = qg + (size_t)bh * 131072;
  const unsigned short* kfp = kg + (size_t)bh * 131072;
  const unsigned short* vfp = vtg + (size_t)bh * 131072;
  const int b = bh >> 4, h = bh & 15;

  bf16x8 qf[4];
#pragma unroll
  for (int ks = 0; ks < 4; ++ks)
    qf[ks] = *reinterpret_cast<const bf16x8*>(&qfp[((size_t)pos * 4 + ks) * 512 + lane * 8]);

  f32x16 oA = zero16(), oB = zero16();
  float mrun = -3.0e38f, lrun = 0.0f;

  // stage: kv-tile t is 4096 contiguous elems (8KB) in fragment-major layout.
  // One gload per thread per matrix; dest = wave-uniform base (w*512 elems).
  auto stage = [&](int bf, int t) {
    GLOAD_LDS(&kfp[(size_t)t * 4096 + tid * 8], &Ks[bf][w * 512]);
    GLOAD_LDS(&vfp[(size_t)t * 4096 + tid * 8], &Vs[bf][w * 512]);
  };

  stage(0, 0);
  __syncthreads();
  int buf = 0;
  for (int t = 0; t < maxT; ++t) {
    if (t + 1 < maxT) stage(buf ^ 1, t + 1);  // in flight under compute
    if (t < myt) {                            // wave-uniform predicate
      // QK^T (swapped): frags from LDS, tight live ranges
      f32x16 sA = zero16(), sB = zero16();
      __builtin_amdgcn_s_setprio(1);
#pragma unroll
      for (int ks = 0; ks < 4; ++ks) {
        bf16x8 ka = *reinterpret_cast<const bf16x8*>(&Ks[buf][ks * 512 + lane * 8]);
        bf16x8 kb = *reinterpret_cast<const bf16x8*>(&Ks[buf][(4 + ks) * 512 + lane * 8]);
        sA = __builtin_amdgcn_mfma_f32_32x32x16_bf16(ka, qf[ks], sA, 0, 0, 0);
        sB = __builtin_amdgcn_mfma_f32_32x32x16_bf16(kb, qf[ks], sB, 0, 0, 0);
      }
      __builtin_amdgcn_s_setprio(0);
      // causal mask (only final tile can contain future keys)
      if (t == myt - 1) {
        const int kvb = t * 64;
#pragma unroll
        for (int r = 0; r < 16; ++r) {
          int keyA = kvb + (r & 3) + 8 * (r >> 2) + 4 * hi;
          if (keyA > qrow) sA[r] = -1e30f;
          if (keyA + 32 > qrow) sB[r] = -1e30f;
        }
      }
      // in-register online softmax (per-lane scalars)
      float tr[16];
#pragma unroll
      for (int k2 = 0; k2 < 16; ++k2) tr[k2] = fmaxf(sA[k2], sB[k2]);
#pragma unroll
      for (int k2 = 0; k2 < 8; ++k2) tr[k2] = fmaxf(tr[k2], tr[k2 + 8]);
#pragma unroll
      for (int k2 = 0; k2 < 4; ++k2) tr[k2] = fmaxf(tr[k2], tr[k2 + 4]);
      float tm = fmaxf(fmaxf(tr[0], tr[1]), fmaxf(tr[2], tr[3]));
      tm = fmaxf(tm, __shfl_xor(tm, 32));
      // T13 defer-max
      if (!__all(tm - mrun <= 8.0f)) {
        float mnew = fmaxf(mrun, tm);
        float alpha = __expf(mrun - mnew);
        lrun *= alpha;
#pragma unroll
        for (int k2 = 0; k2 < 16; ++k2) {
          oA[k2] *= alpha;
          oB[k2] *= alpha;
        }
        mrun = mnew;
      }
#pragma unroll
      for (int k2 = 0; k2 < 16; ++k2) {
        sA[k2] = __expf(sA[k2] - mrun);
        sB[k2] = __expf(sB[k2] - mrun);
      }
      float sr[16];
#pragma unroll
      for (int k2 = 0; k2 < 16; ++k2) sr[k2] = sA[k2] + sB[k2];
#pragma unroll
      for (int k2 = 0; k2 < 8; ++k2) sr[k2] += sr[k2 + 8];
#pragma unroll
      for (int k2 = 0; k2 < 4; ++k2) sr[k2] += sr[k2 + 4];
      float lsum = (sr[0] + sr[1]) + (sr[2] + sr[3]);
      lsum += __shfl_xor(lsum, 32);
      lrun += lsum;
      // T12: P -> B-operand fragments in registers
      unsigned int ua[4], va[4], ub[4], vb[4];
#pragma unroll
      for (int m = 0; m < 4; ++m) {
        asm("v_cvt_pk_bf16_f32 %0, %1, %2" : "=v"(ua[m]) : "v"(sA[4 * m]), "v"(sA[4 * m + 1]));
        asm("v_cvt_pk_bf16_f32 %0, %1, %2" : "=v"(va[m]) : "v"(sA[4 * m + 2]), "v"(sA[4 * m + 3]));
        asm("v_cvt_pk_bf16_f32 %0, %1, %2" : "=v"(ub[m]) : "v"(sB[4 * m]), "v"(sB[4 * m + 1]));
        asm("v_cvt_pk_bf16_f32 %0, %1, %2" : "=v"(vb[m]) : "v"(sB[4 * m + 2]), "v"(sB[4 * m + 3]));
      }
      asm("v_permlane32_swap_b32 %0, %1" : "+v"(ua[0]), "+v"(ua[1]));
      asm("v_permlane32_swap_b32 %0, %1" : "+v"(va[0]), "+v"(va[1]));
      asm("v_permlane32_swap_b32 %0, %1" : "+v"(ua[2]), "+v"(ua[3]));
      asm("v_permlane32_swap_b32 %0, %1" : "+v"(va[2]), "+v"(va[3]));
      asm("v_permlane32_swap_b32 %0, %1" : "+v"(ub[0]), "+v"(ub[1]));
      asm("v_permlane32_swap_b32 %0, %1" : "+v"(vb[0]), "+v"(vb[1]));
      asm("v_permlane32_swap_b32 %0, %1" : "+v"(ub[2]), "+v"(ub[3]));
      asm("v_permlane32_swap_b32 %0, %1" : "+v"(vb[2]), "+v"(vb[3]));
      u32x4 w0 = {ua[0], va[0], ua[1], va[1]};
      u32x4 w1 = {ua[2], va[2], ua[3], va[3]};
      u32x4 w2 = {ub[0], vb[0], ub[1], vb[1]};
      u32x4 w3 = {ub[2], vb[2], ub[3], vb[3]};
      bf16x8 pf0 = __builtin_bit_cast(bf16x8, w0);
      bf16x8 pf1 = __builtin_bit_cast(bf16x8, w1);
      bf16x8 pf2 = __builtin_bit_cast(bf16x8, w2);
      bf16x8 pf3 = __builtin_bit_cast(bf16x8, w3);
      // PV: O^T += mfma(V^T, P); V frags from LDS
      __builtin_amdgcn_s_setprio(1);
      {
        bf16x8 v0 = *reinterpret_cast<const bf16x8*>(&Vs[buf][0 * 512 + lane * 8]);
        bf16x8 v4 = *reinterpret_cast<const bf16x8*>(&Vs[buf][4 * 512 + lane * 8]);
        oA = __builtin_amdgcn_mfma_f32_32x32x16_bf16(v0, pf0, oA, 0, 0, 0);
        oB = __builtin_amdgcn_mfma_f32_32x32x16_bf16(v4, pf0, oB, 0, 0, 0);
        bf16x8 v1 = *reinterpret_cast<const bf16x8*>(&Vs[buf][1 * 512 + lane * 8]);
        bf16x8 v5 = *reinterpret_cast<const bf16x8*>(&Vs[buf][5 * 512 + lane * 8]);
        oA = __builtin_amdgcn_mfma_f32_32x32x16_bf16(v1, pf1, oA, 0, 0, 0);
        oB = __builtin_amdgcn_mfma_f32_32x32x16_bf16(v5, pf1, oB, 0, 0, 0);
        bf16x8 v2 = *reinterpret_cast<const bf16x8*>(&Vs[buf][2 * 512 + lane * 8]);
        bf16x8 v6 = *reinterpret_cast<const bf16x8*>(&Vs[buf][6 * 512 + lane * 8]);
        oA = __builtin_amdgcn_mfma_f32_32x32x16_bf16(v2, pf2, oA, 0, 0, 0);
        oB = __builtin_amdgcn_mfma_f32_32x32x16_bf16(v6, pf2, oB, 0, 0, 0);
        bf16x8 v3 = *reinterpret_cast<const bf16x8*>(&Vs[buf][3 * 512 + lane * 8]);
        bf16x8 v7 = *reinterpret_cast<const bf16x8*>(&Vs[buf][7 * 512 + lane * 8]);
        oA = __builtin_amdgcn_mfma_f32_32x32x16_bf16(v3, pf3, oA, 0, 0, 0);
        oB = __builtin_amdgcn_mfma_f32_32x32x16_bf16(v7, pf3, oB, 0, 0, 0);
      }
      __builtin_amdgcn_s_setprio(0);
    }
    __syncthreads();  // all reads of buf done + my gloads for buf^1 landed
    buf ^= 1;
  }

  const float inv = 1.0f / lrun;
  const size_t obase = ((size_t)b * T_SEQ + qrow) * CDIM + h * HD;
#pragma unroll
  for (int g2 = 0; g2 < 4; ++g2) {
    us4 pa, pb;
#pragma unroll
    for (int jj = 0; jj < 4; ++jj) {
      pa[jj] = f2bf(oA[4 * g2 + jj] * inv);
      pb[jj] = f2bf(oB[4 * g2 + jj] * inv);
    }
    *reinterpret_cast<us4*>(&att[obase + g2 * 8 + 4 * hi]) = pa;
    *reinterpret_cast<us4*>(&att[obase + 32 + g2 * 8 + 4 * hi]) = pb;
  }
}

extern "C" void kernel_launch(void* const* d_in, const int* in_sizes, int n_in,
                              void* d_out, int out_size, void* d_ws, size_t ws_size,
                              hipStream_t stream) {
  const float* x = (const float*)d_in[0];
  const float* Wq = (const float*)d_in[1];
  const float* Wkv = (const float*)d_in[2];
  const float* Wc = (const float*)d_in[3];
  float* out = (float*)d_out;

  char* ws = (char*)d_ws;
  size_t off = 0;
  auto alloc = [&](size_t bytes) {
    void* p = ws + off;
    off += (bytes + 255) & ~(size_t)255;
    return p;
  };
  const size_t NTOK = 4ull * T_SEQ;            // 8192
  const size_t NELEM = NTOK * CDIM;            // 8388608
  unsigned short* xb = (unsigned short*)alloc(NELEM * 2);   // also reused for att
  unsigned short* WT = (unsigned short*)alloc(3072ull * 1024 * 2);
  unsigned short* WcT = (unsigned short*)alloc(1024ull * 1024 * 2);
  unsigned short* qb = (unsigned short*)alloc(NELEM * 2);
  unsigned short* kb = (unsigned short*)alloc(NELEM * 2);
  unsigned short* vT = (unsigned short*)alloc(NELEM * 2);
  float* cost = (float*)alloc(T_SEQ * 32 * 4);
  float* sint = (float*)alloc(T_SEQ * 32 * 4);
  unsigned short* att = xb;  // xb dead after gemm<1>; reuse for attention output

  cast_x_kernel<<<(int)(NELEM / 4 / 256), 256, 0, stream>>>(x, xb, (int)(NELEM / 4));
  transpose_cast_kernel<<<dim3(32, 32), dim3(32, 8), 0, stream>>>(Wq, WT, 1024, 1024);
  transpose_cast_kernel<<<dim3(64, 32), dim3(32, 8), 0, stream>>>(Wkv, WT + 1024 * 1024, 2048,
                                                                  1024);
  transpose_cast_kernel<<<dim3(32, 32), dim3(32, 8), 0, stream>>>(Wc, WcT, 1024, 1024);
  rope_table_kernel<<<T_SEQ * 32 / 256, 256, 0, stream>>>(cost, sint);

  gemm_kernel<1><<<dim3(3072 / 128, NTOK / 128), 256, 0, stream>>>(
      xb, WT, (int)NTOK, 3072, 1024, qb, kb, vT, cost, sint, nullptr);

  attn_kernel<<<dim3(512), 512, 0, stream>>>(qb, kb, vT, att);

  gemm_kernel<0><<<dim3(1024 / 128, NTOK / 128), 256, 0, stream>>>(
      att, WcT, (int)NTOK, 1024, 1024, nullptr, nullptr, nullptr, nullptr, nullptr, out);
}